// Round 1
// baseline (1507.432 us; speedup 1.0000x reference)
//
#include <hip/hip_runtime.h>
#include <cstdint>
#include <cstddef>

typedef unsigned short u16;
typedef __attribute__((ext_vector_type(8))) short bf16x8;   // 8 bf16 = 4 VGPRs
typedef __attribute__((ext_vector_type(4))) float f32x4;    // MFMA 16x16 C/D

using gas_ptr = const __attribute__((address_space(1))) void*;
using las_ptr = __attribute__((address_space(3))) void*;

__device__ __forceinline__ u16 f2bf(float f) {
  union { float f; unsigned int u; } v; v.f = f;
  unsigned int u = v.u;
  return (u16)((u + 0x7fffu + ((u >> 16) & 1u)) >> 16);  // RNE
}

// ---------------- elementwise fp32 -> bf16 convert (vectorized x4) ----------------
__global__ __launch_bounds__(256) void cvt_f32_bf16(const float* __restrict__ src,
                                                    u16* __restrict__ dst, int n) {
  int i = (blockIdx.x * 256 + threadIdx.x) * 4;
  if (i >= n) return;
  float4 v = *(const float4*)(src + i);
  ushort4 o;
  o.x = f2bf(v.x); o.y = f2bf(v.y); o.z = f2bf(v.z); o.w = f2bf(v.w);
  *(ushort4*)(dst + i) = o;
}

// ---------------- m97-style bf16 GEMM: C[M,N] = A[M,K] * B[N,K]^T (fp32 out) ------
__global__ __launch_bounds__(256) void gemm_bt(const u16* __restrict__ A,
                                               const u16* __restrict__ B,
                                               float* __restrict__ C,
                                               int M, int N, int K) {
  __shared__ u16 As[128][32];
  __shared__ u16 Bs[128][32];
  const int m0 = blockIdx.y * 128, n0 = blockIdx.x * 128;
  const int tid = threadIdx.x;
  const int wave = tid >> 6, lane = tid & 63;
  const int wm = (wave & 1) * 64, wn = (wave >> 1) * 64;
  const int srow = lane >> 2, skoff = (lane & 3) * 8;   // staging: 4 lanes/row, 8 elem each
  const int col = lane & 15, quad = lane >> 4;
  f32x4 acc[4][4] = {};
  for (int k0 = 0; k0 < K; k0 += 32) {
#pragma unroll
    for (int r = 0; r < 2; ++r) {
      const u16* ga = A + (size_t)(m0 + r * 64 + wave * 16 + srow) * K + k0 + skoff;
      const u16* gb = B + (size_t)(n0 + r * 64 + wave * 16 + srow) * K + k0 + skoff;
      __builtin_amdgcn_global_load_lds((gas_ptr)ga, (las_ptr)&As[r * 64 + wave * 16][0], 16, 0, 0);
      __builtin_amdgcn_global_load_lds((gas_ptr)gb, (las_ptr)&Bs[r * 64 + wave * 16][0], 16, 0, 0);
    }
    __syncthreads();
    bf16x8 af[4], bfr[4];
#pragma unroll
    for (int t = 0; t < 4; ++t) {
      af[t]  = *(const bf16x8*)&As[wm + t * 16 + col][quad * 8];
      bfr[t] = *(const bf16x8*)&Bs[wn + t * 16 + col][quad * 8];
    }
#pragma unroll
    for (int mt = 0; mt < 4; ++mt)
#pragma unroll
      for (int nt = 0; nt < 4; ++nt)
        acc[mt][nt] = __builtin_amdgcn_mfma_f32_16x16x32_bf16(af[mt], bfr[nt], acc[mt][nt], 0, 0, 0);
    __syncthreads();
  }
#pragma unroll
  for (int mt = 0; mt < 4; ++mt)
#pragma unroll
    for (int nt = 0; nt < 4; ++nt)
#pragma unroll
      for (int r = 0; r < 4; ++r) {
        const int row  = m0 + wm + mt * 16 + quad * 4 + r;   // C layout: row=(lane>>4)*4+reg
        const int ccol = n0 + wn + nt * 16 + col;            //           col=lane&15
        C[(size_t)row * N + ccol] = acc[mt][nt][r];
      }
}

// ---------------- RoPE on Q: QKV32 fp32 -> Qb bf16 (b,h,s,d) ----------------------
__global__ __launch_bounds__(256) void rope_q_kernel(const float* __restrict__ qkv,
                                                     const float* __restrict__ rope,
                                                     u16* __restrict__ Qb) {
  int idx = blockIdx.x * 256 + threadIdx.x;           // (bh, s, pair) : 64*1024*64
  int i = idx & 63, s = (idx >> 6) & 1023, bh = idx >> 16;
  int b = bh >> 5, h = bh & 31;
  const float* p = qkv + (size_t)(b * 1024 + s) * 12288 + h * 128 + 2 * i;
  float t0 = p[0], t1 = p[1];
  float c = rope[(s * 64 + i) * 2], sn = rope[(s * 64 + i) * 2 + 1];
  size_t o = ((size_t)bh * 1024 + s) * 128 + 2 * i;
  Qb[o]     = f2bf(t0 * c - t1 * sn);
  Qb[o + 1] = f2bf(t0 * sn + t1 * c);
}

// ---------------- RoPE on K: QKV32 fp32 -> d_out xk fp32 at positions >= 1024 ------
__global__ __launch_bounds__(256) void rope_k_kernel(const float* __restrict__ qkv,
                                                     const float* __restrict__ rope,
                                                     float* __restrict__ xk) {
  int idx = blockIdx.x * 256 + threadIdx.x;
  int i = idx & 63, s = (idx >> 6) & 1023, bh = idx >> 16;
  int b = bh >> 5, h = bh & 31;
  const float* p = qkv + (size_t)(b * 1024 + s) * 12288 + 4096 + h * 128 + 2 * i;
  float t0 = p[0], t1 = p[1];
  float c = rope[(s * 64 + i) * 2], sn = rope[(s * 64 + i) * 2 + 1];
  size_t o = ((size_t)bh * 2048 + 1024 + s) * 128 + 2 * i;
  xk[o]     = t0 * c - t1 * sn;
  xk[o + 1] = t0 * sn + t1 * c;
}

// ---------------- V: QKV32 fp32 -> d_out xv fp32 at positions >= 1024 --------------
__global__ __launch_bounds__(256) void copy_v_kernel(const float* __restrict__ qkv,
                                                     float* __restrict__ xv) {
  int idx = blockIdx.x * 256 + threadIdx.x;           // (bh, s, d) : 64*1024*128
  int d = idx & 127, s = (idx >> 7) & 1023, bh = idx >> 17;
  int b = bh >> 5, h = bh & 31;
  xv[((size_t)bh * 2048 + 1024 + s) * 128 + d] =
      qkv[(size_t)(b * 1024 + s) * 12288 + 8192 + h * 128 + d];
}

// ---------------- cache copy: (b,h,1024,128) -> dst (b,h,2048,128) at t < 1024 -----
__global__ __launch_bounds__(256) void cache_copy_kernel(const float* __restrict__ src,
                                                         float* __restrict__ dst) {
  int idx = blockIdx.x * 256 + threadIdx.x;           // 64*1024*128
  int d = idx & 127, t = (idx >> 7) & 1023, bh = idx >> 17;
  dst[((size_t)bh * 2048 + t) * 128 + d] = src[idx];
}

// ---------------- transpose: xv fp32 (bh, 2048 t, 128 d) -> VT bf16 (bh, 128 d, 2048 t)
__global__ __launch_bounds__(256) void transpose_v_kernel(const float* __restrict__ src,
                                                          u16* __restrict__ dst) {
  __shared__ float tile[32][33];
  int bh = blockIdx.z;
  int t0 = blockIdx.x * 32, d0 = blockIdx.y * 32;
  int tx = threadIdx.x & 31, ty = threadIdx.x >> 5;   // ty: 0..7
  const float* s = src + ((size_t)bh * 2048 + t0) * 128 + d0;
#pragma unroll
  for (int i = 0; i < 4; ++i)
    tile[ty + i * 8][tx] = s[(ty + i * 8) * 128 + tx];
  __syncthreads();
  u16* dp = dst + ((size_t)bh * 128 + d0) * 2048 + t0;
#pragma unroll
  for (int i = 0; i < 4; ++i)
    dp[(ty + i * 8) * 2048 + tx] = f2bf(tile[tx][ty + i * 8]);
}

// ---------------- flash attention: 1 block = (bh, 64 q rows), 4 waves x 16 rows ----
__global__ __launch_bounds__(256) void attn_kernel(const u16* __restrict__ Qb,
                                                   const u16* __restrict__ Kb,
                                                   const u16* __restrict__ VT,
                                                   u16* __restrict__ ctx) {
  const int bh = blockIdx.y;
  const int b = bh >> 5, h = bh & 31;
  const int wave = threadIdx.x >> 6, lane = threadIdx.x & 63;
  const int col = lane & 15, quad = lane >> 4;
  const int q0 = blockIdx.x * 64 + wave * 16;

  __shared__ u16 Plds[4][16][32];   // per-wave P round-trip (C-layout -> A-layout)

  const u16* Qh = Qb + (size_t)bh * 1024 * 128;
  const u16* Kh = Kb + (size_t)bh * 2048 * 128;
  const u16* Vh = VT + (size_t)bh * 128 * 2048;

  bf16x8 qf[4];
#pragma unroll
  for (int kc = 0; kc < 4; ++kc)
    qf[kc] = *(const bf16x8*)&Qh[(q0 + col) * 128 + kc * 32 + quad * 8];

  f32x4 o[8] = {};
  float mrow[4], lrow[4];
#pragma unroll
  for (int r = 0; r < 4; ++r) { mrow[r] = -1e30f; lrow[r] = 0.0f; }

  const int t_end = 1024 + blockIdx.x * 64 + 64;
  const float scale = 0.08838834764831845f;   // 1/sqrt(128)

  for (int t0 = 0; t0 < t_end; t0 += 32) {
    f32x4 s0 = {0.f, 0.f, 0.f, 0.f}, s1 = {0.f, 0.f, 0.f, 0.f};
#pragma unroll
    for (int kc = 0; kc < 4; ++kc) {
      bf16x8 k0f = *(const bf16x8*)&Kh[(t0 + col) * 128 + kc * 32 + quad * 8];
      bf16x8 k1f = *(const bf16x8*)&Kh[(t0 + 16 + col) * 128 + kc * 32 + quad * 8];
      s0 = __builtin_amdgcn_mfma_f32_16x16x32_bf16(qf[kc], k0f, s0, 0, 0, 0);
      s1 = __builtin_amdgcn_mfma_f32_16x16x32_bf16(qf[kc], k1f, s1, 0, 0, 0);
    }
    float p0[4], p1[4];
#pragma unroll
    for (int r = 0; r < 4; ++r) {
      const int qabs = 1024 + q0 + quad * 4 + r;
      float v0 = s0[r] * scale, v1 = s1[r] * scale;
      if (t0 + col > qabs)      v0 = -1e30f;   // causal mask
      if (t0 + 16 + col > qabs) v1 = -1e30f;
      p0[r] = v0; p1[r] = v1;
    }
#pragma unroll
    for (int r = 0; r < 4; ++r) {
      float mx = fmaxf(p0[r], p1[r]);          // row reduce across 16 cols (same 16-lane group)
      mx = fmaxf(mx, __shfl_xor(mx, 1));
      mx = fmaxf(mx, __shfl_xor(mx, 2));
      mx = fmaxf(mx, __shfl_xor(mx, 4));
      mx = fmaxf(mx, __shfl_xor(mx, 8));
      const float mnew  = fmaxf(mrow[r], mx);
      const float alpha = __expf(mrow[r] - mnew);
      mrow[r] = mnew;
      const float e0 = __expf(p0[r] - mnew);
      const float e1 = __expf(p1[r] - mnew);
      p0[r] = e0; p1[r] = e1;
      float rs = e0 + e1;
      rs += __shfl_xor(rs, 1);
      rs += __shfl_xor(rs, 2);
      rs += __shfl_xor(rs, 4);
      rs += __shfl_xor(rs, 8);
      lrow[r] = lrow[r] * alpha + rs;
#pragma unroll
      for (int dt = 0; dt < 8; ++dt) o[dt][r] *= alpha;
    }
    // P: C-layout -> A-operand layout via wave-private LDS
#pragma unroll
    for (int r = 0; r < 4; ++r) {
      Plds[wave][quad * 4 + r][col]      = f2bf(p0[r]);
      Plds[wave][quad * 4 + r][col + 16] = f2bf(p1[r]);
    }
    asm volatile("s_waitcnt lgkmcnt(0)" ::: "memory");
    const bf16x8 pf = *(const bf16x8*)&Plds[wave][col][quad * 8];
#pragma unroll
    for (int dt = 0; dt < 8; ++dt) {
      bf16x8 vf = *(const bf16x8*)&Vh[(dt * 16 + col) * 2048 + t0 + quad * 8];
      o[dt] = __builtin_amdgcn_mfma_f32_16x16x32_bf16(pf, vf, o[dt], 0, 0, 0);
    }
    asm volatile("s_waitcnt lgkmcnt(0)" ::: "memory");
  }

  float inv[4];
#pragma unroll
  for (int r = 0; r < 4; ++r) inv[r] = 1.0f / lrow[r];
#pragma unroll
  for (int dt = 0; dt < 8; ++dt)
#pragma unroll
    for (int r = 0; r < 4; ++r) {
      const int q = q0 + quad * 4 + r;
      const int d = dt * 16 + col;
      ctx[(size_t)(b * 1024 + q) * 4096 + h * 128 + d] = f2bf(o[dt][r] * inv[r]);
    }
}

// ----------------------------------------------------------------------------------
extern "C" void kernel_launch(void* const* d_in, const int* in_sizes, int n_in,
                              void* d_out, int out_size, void* d_ws, size_t ws_size,
                              hipStream_t stream) {
  const float* x    = (const float*)d_in[0];
  const float* kc   = (const float*)d_in[1];
  const float* vc   = (const float*)d_in[2];
  const float* rope = (const float*)d_in[3];
  const float* Wq   = (const float*)d_in[4];
  const float* Wk   = (const float*)d_in[5];
  const float* Wv   = (const float*)d_in[6];
  const float* Wo   = (const float*)d_in[7];

  float* out = (float*)d_out;                 // (2,1024,4096)
  float* xk  = out + 8388608;                 // (2,32,2048,128)
  float* xv  = out + 25165824;                // (2,32,2048,128)

  char* ws = (char*)d_ws;
  // workspace layout (bytes), with aliasing (stream-ordered reuse):
  u16*   Xb   = (u16*)(ws + 0);               // x bf16          16,777,216 B
  u16*   Wc   = (u16*)(ws + 16777216);        // Wqkv bf16      100,663,296 B
  u16*   KbB  = (u16*)(ws + 16777216);        //   after GEMM1: K bf16 (b,h,2048,128)  33,554,432 B
  u16*   VTb  = (u16*)(ws + 50331648);        //   after GEMM1: V^T bf16 (b,h,128,2048) 33,554,432 B
  float* QKV  = (float*)(ws + 117440512);     // QKV fp32 (2048 x 12288)  100,663,296 B
  u16*   Wob  = (u16*)(ws + 117440512);       //   after rope: Wo bf16    33,554,432 B
  u16*   ctxb = (u16*)(ws + 150994944);       //   after rope: ctx bf16   16,777,216 B
  u16*   Qbb  = (u16*)(ws + 218103808);       // Q bf16 (b,h,1024,128)    16,777,216 B

  // 1) converts
  cvt_f32_bf16<<<8192, 256, 0, stream>>>(x, Xb, 8388608);
  cvt_f32_bf16<<<16384, 256, 0, stream>>>(Wq, Wc, 16777216);
  cvt_f32_bf16<<<16384, 256, 0, stream>>>(Wk, Wc + 16777216, 16777216);
  cvt_f32_bf16<<<16384, 256, 0, stream>>>(Wv, Wc + 33554432, 16777216);
  // 2) fused QKV projection: (2048 x 4096) @ (12288 x 4096)^T
  gemm_bt<<<dim3(96, 16), 256, 0, stream>>>(Xb, Wc, QKV, 2048, 12288, 4096);
  // 3) RoPE + scatter to outputs / attention operands
  rope_q_kernel<<<16384, 256, 0, stream>>>(QKV, rope, Qbb);
  rope_k_kernel<<<16384, 256, 0, stream>>>(QKV, rope, xk);
  copy_v_kernel<<<32768, 256, 0, stream>>>(QKV, xv);
  cache_copy_kernel<<<32768, 256, 0, stream>>>(kc, xk);
  cache_copy_kernel<<<32768, 256, 0, stream>>>(vc, xv);
  // 4) bf16 operands for attention (K same layout; V transposed)
  cvt_f32_bf16<<<32768, 256, 0, stream>>>(xk, KbB, 33554432);
  transpose_v_kernel<<<dim3(64, 4, 64), 256, 0, stream>>>(xv, VTb);
  cvt_f32_bf16<<<16384, 256, 0, stream>>>(Wo, Wob, 16777216);
  // 5) flash attention -> ctx bf16 (2048 x 4096)
  attn_kernel<<<dim3(16, 64), 256, 0, stream>>>(Qbb, KbB, VTb, ctxb);
  // 6) output projection
  gemm_bt<<<dim3(32, 16), 256, 0, stream>>>(ctxb, Wob, out, 2048, 4096, 4096);
}

// Round 3
// 1044.775 us; speedup vs baseline: 1.4428x; 1.4428x over previous
//
#include <hip/hip_runtime.h>
#include <cstdint>
#include <cstddef>

typedef unsigned short u16;
typedef __attribute__((ext_vector_type(8))) short bf16x8;   // 8 bf16 = 4 VGPRs
typedef __attribute__((ext_vector_type(4))) float f32x4;    // MFMA 16x16 C/D

using gas_ptr = const __attribute__((address_space(1))) void*;
using las_ptr = __attribute__((address_space(3))) void*;

__device__ __forceinline__ u16 f2bf(float f) {
  union { float f; unsigned int u; } v; v.f = f;
  unsigned int u = v.u;
  return (u16)((u + 0x7fffu + ((u >> 16) & 1u)) >> 16);  // RNE
}

__device__ __forceinline__ float fast_exp2(float x) {
  return __builtin_amdgcn_exp2f(x);   // raw v_exp_f32
}

// ---------------- elementwise fp32 -> bf16 convert (vectorized x4) ----------------
__global__ __launch_bounds__(256) void cvt_f32_bf16(const float* __restrict__ src,
                                                    u16* __restrict__ dst, int n) {
  int i = (blockIdx.x * 256 + threadIdx.x) * 4;
  if (i >= n) return;
  float4 v = *(const float4*)(src + i);
  ushort4 o;
  o.x = f2bf(v.x); o.y = f2bf(v.y); o.z = f2bf(v.z); o.w = f2bf(v.w);
  *(ushort4*)(dst + i) = o;
}

// ---------------- m97-style bf16 GEMM: C[M,N] = A[M,K] * B[N,K]^T (fp32 out) ------
__global__ __launch_bounds__(256) void gemm_bt(const u16* __restrict__ A,
                                               const u16* __restrict__ B,
                                               float* __restrict__ C,
                                               int M, int N, int K) {
  __shared__ u16 As[128][32];
  __shared__ u16 Bs[128][32];
  const int m0 = blockIdx.y * 128, n0 = blockIdx.x * 128;
  const int tid = threadIdx.x;
  const int wave = tid >> 6, lane = tid & 63;
  const int wm = (wave & 1) * 64, wn = (wave >> 1) * 64;
  const int srow = lane >> 2, skoff = (lane & 3) * 8;
  const int col = lane & 15, quad = lane >> 4;
  f32x4 acc[4][4] = {};
  for (int k0 = 0; k0 < K; k0 += 32) {
#pragma unroll
    for (int r = 0; r < 2; ++r) {
      const u16* ga = A + (size_t)(m0 + r * 64 + wave * 16 + srow) * K + k0 + skoff;
      const u16* gb = B + (size_t)(n0 + r * 64 + wave * 16 + srow) * K + k0 + skoff;
      __builtin_amdgcn_global_load_lds((gas_ptr)ga, (las_ptr)&As[r * 64 + wave * 16][0], 16, 0, 0);
      __builtin_amdgcn_global_load_lds((gas_ptr)gb, (las_ptr)&Bs[r * 64 + wave * 16][0], 16, 0, 0);
    }
    __syncthreads();
    bf16x8 af[4], bfr[4];
#pragma unroll
    for (int t = 0; t < 4; ++t) {
      af[t]  = *(const bf16x8*)&As[wm + t * 16 + col][quad * 8];
      bfr[t] = *(const bf16x8*)&Bs[wn + t * 16 + col][quad * 8];
    }
#pragma unroll
    for (int mt = 0; mt < 4; ++mt)
#pragma unroll
      for (int nt = 0; nt < 4; ++nt)
        acc[mt][nt] = __builtin_amdgcn_mfma_f32_16x16x32_bf16(af[mt], bfr[nt], acc[mt][nt], 0, 0, 0);
    __syncthreads();
  }
#pragma unroll
  for (int mt = 0; mt < 4; ++mt)
#pragma unroll
    for (int nt = 0; nt < 4; ++nt)
#pragma unroll
      for (int r = 0; r < 4; ++r) {
        const int row  = m0 + wm + mt * 16 + quad * 4 + r;
        const int ccol = n0 + wn + nt * 16 + col;
        C[(size_t)row * N + ccol] = acc[mt][nt][r];
      }
}

// ---------------- RoPE on Q (scale*log2e folded): QKV32 fp32 -> Qb bf16 -----------
__global__ __launch_bounds__(256) void rope_q_kernel(const float* __restrict__ qkv,
                                                     const float* __restrict__ rope,
                                                     u16* __restrict__ Qb) {
  const float qs = 0.08838834764831845f * 1.4426950408889634f;  // 1/sqrt(128) * log2(e)
  int idx = blockIdx.x * 256 + threadIdx.x;           // (bh, s, pair) : 64*1024*64
  int i = idx & 63, s = (idx >> 6) & 1023, bh = idx >> 16;
  int b = bh >> 5, h = bh & 31;
  const float* p = qkv + (size_t)(b * 1024 + s) * 12288 + h * 128 + 2 * i;
  float t0 = p[0], t1 = p[1];
  float c = rope[(s * 64 + i) * 2], sn = rope[(s * 64 + i) * 2 + 1];
  size_t o = ((size_t)bh * 1024 + s) * 128 + 2 * i;
  Qb[o]     = f2bf((t0 * c - t1 * sn) * qs);
  Qb[o + 1] = f2bf((t0 * sn + t1 * c) * qs);
}

// ---------------- RoPE on K: fp32 -> xk (d_out) AND Kb bf16, positions >= 1024 ----
__global__ __launch_bounds__(256) void rope_k_kernel(const float* __restrict__ qkv,
                                                     const float* __restrict__ rope,
                                                     float* __restrict__ xk,
                                                     u16* __restrict__ Kb) {
  int idx = blockIdx.x * 256 + threadIdx.x;
  int i = idx & 63, s = (idx >> 6) & 1023, bh = idx >> 16;
  int b = bh >> 5, h = bh & 31;
  const float* p = qkv + (size_t)(b * 1024 + s) * 12288 + 4096 + h * 128 + 2 * i;
  float t0 = p[0], t1 = p[1];
  float c = rope[(s * 64 + i) * 2], sn = rope[(s * 64 + i) * 2 + 1];
  float r0 = t0 * c - t1 * sn, r1 = t0 * sn + t1 * c;
  size_t o = ((size_t)bh * 2048 + 1024 + s) * 128 + 2 * i;
  xk[o] = r0; xk[o + 1] = r1;
  Kb[o] = f2bf(r0); Kb[o + 1] = f2bf(r1);
}

// ---------------- V new positions: fp32 -> xv (d_out), positions >= 1024 ----------
__global__ __launch_bounds__(256) void copy_v_kernel(const float* __restrict__ qkv,
                                                     float* __restrict__ xv) {
  int idx = blockIdx.x * 256 + threadIdx.x;           // (bh, s, d) : 64*1024*128
  int d = idx & 127, s = (idx >> 7) & 1023, bh = idx >> 17;
  int b = bh >> 5, h = bh & 31;
  xv[((size_t)bh * 2048 + 1024 + s) * 128 + d] =
      qkv[(size_t)(b * 1024 + s) * 12288 + 8192 + h * 128 + d];
}

// ---------------- K cache: fp32 -> xk fp32 + Kb bf16 at t < 1024 ------------------
__global__ __launch_bounds__(256) void cache_copy_k_kernel(const float* __restrict__ src,
                                                           float* __restrict__ dst,
                                                           u16* __restrict__ dstb) {
  int idx = blockIdx.x * 256 + threadIdx.x;           // 64*1024*128
  int d = idx & 127, t = (idx >> 7) & 1023, bh = idx >> 17;
  float v = src[idx];
  size_t o = ((size_t)bh * 2048 + t) * 128 + d;
  dst[o] = v;
  dstb[o] = f2bf(v);
}

// ---------------- V cache: fp32 -> xv fp32 at t < 1024 ----------------------------
__global__ __launch_bounds__(256) void cache_copy_v_kernel(const float* __restrict__ src,
                                                           float* __restrict__ dst) {
  int idx = blockIdx.x * 256 + threadIdx.x;
  int d = idx & 127, t = (idx >> 7) & 1023, bh = idx >> 17;
  dst[((size_t)bh * 2048 + t) * 128 + d] = src[idx];
}

// ---------------- transpose: xv fp32 (bh, 2048 t, 128 d) -> VT bf16 (bh, 128 d, 2048 t)
__global__ __launch_bounds__(256) void transpose_v_kernel(const float* __restrict__ src,
                                                          u16* __restrict__ dst) {
  __shared__ float tile[32][33];
  int bh = blockIdx.z;
  int t0 = blockIdx.x * 32, d0 = blockIdx.y * 32;
  int tx = threadIdx.x & 31, ty = threadIdx.x >> 5;
  const float* s = src + ((size_t)bh * 2048 + t0) * 128 + d0;
#pragma unroll
  for (int i = 0; i < 4; ++i)
    tile[ty + i * 8][tx] = s[(ty + i * 8) * 128 + tx];
  __syncthreads();
  u16* dp = dst + ((size_t)bh * 128 + d0) * 2048 + t0;
#pragma unroll
  for (int i = 0; i < 4; ++i)
    dp[(ty + i * 8) * 2048 + tx] = f2bf(tile[tx][ty + i * 8]);
}

// ---------------- flash attention v2: 1 block = (bh, 128 q rows), LDS K/V staging --
// wave handles 32 q rows (2 m-tiles of 16); t-step = 64; K/V XOR-swizzled in LDS.
__global__ __launch_bounds__(256, 2) void attn_kernel(const u16* __restrict__ Qb,
                                                      const u16* __restrict__ Kb,
                                                      const u16* __restrict__ VT,
                                                      u16* __restrict__ ctx) {
  const int bh = blockIdx.y;
  const int b = bh >> 5, h = bh & 31;
  const int wave = threadIdx.x >> 6, lane = threadIdx.x & 63;
  const int col = lane & 15, quad = lane >> 4;
  const int qblk = blockIdx.x * 128;
  const int qw = qblk + wave * 32;          // this wave's 32 q rows

  __shared__ u16 Ks[64][128];   // (t, d), chunk-XOR-swizzled: 16 KB
  __shared__ u16 Vs[128][64];   // (d, t), chunk-XOR-swizzled: 16 KB
  __shared__ u16 Plds[4][32][64];  // per-wave P, chunk-XOR-swizzled: 16 KB

  const u16* Qh = Qb + (size_t)bh * 1024 * 128;
  const u16* Kh = Kb + (size_t)bh * 2048 * 128;
  const u16* Vh = VT + (size_t)bh * 128 * 2048;

  // Q fragments: A-operand layout (m = col, k = quad*8 + j within kc*32)
  bf16x8 qf[2][4];
#pragma unroll
  for (int mt = 0; mt < 2; ++mt)
#pragma unroll
    for (int kc = 0; kc < 4; ++kc)
      qf[mt][kc] = *(const bf16x8*)&Qh[(size_t)(qw + mt * 16 + col) * 128 + kc * 32 + quad * 8];

  f32x4 o[2][8] = {};
  float m_r[2][4], l_r[2][4];
#pragma unroll
  for (int mt = 0; mt < 2; ++mt)
#pragma unroll
    for (int r = 0; r < 4; ++r) { m_r[mt][r] = -1e30f; l_r[mt][r] = 0.0f; }

  const int t_end = 1024 + qblk + 128;

  for (int t0 = 0; t0 < t_end; t0 += 64) {
    // ---- stage K tile (64 t x 128 d): 4 issues x 4 waves x (4 rows, 16 chunks) ----
#pragma unroll
    for (int j = 0; j < 4; ++j) {
      const int g = j * 4 + wave;
      const int r = g * 4 + (lane >> 4);              // t row 0..63
      const int cg = (lane & 15) ^ (r & 15);          // source chunk (16B) for XOR swizzle
      __builtin_amdgcn_global_load_lds((gas_ptr)(Kh + (size_t)(t0 + r) * 128 + cg * 8),
                                       (las_ptr)&Ks[g * 4][0], 16, 0, 0);
    }
    // ---- stage V^T tile (128 d x 64 t): 4 issues x 4 waves x (8 rows, 8 chunks) ---
#pragma unroll
    for (int j = 0; j < 4; ++j) {
      const int g = j * 4 + wave;
      const int r = g * 8 + (lane >> 3);              // d row 0..127
      const int cg = (lane & 7) ^ (r & 7);
      __builtin_amdgcn_global_load_lds((gas_ptr)(Vh + (size_t)r * 2048 + t0 + cg * 8),
                                       (las_ptr)&Vs[g * 8][0], 16, 0, 0);
    }
    __syncthreads();

    // ---- QK^T: S[2 mt][4 tt] over K=128 -----------------------------------------
    f32x4 s[2][4];
#pragma unroll
    for (int mt = 0; mt < 2; ++mt)
#pragma unroll
      for (int tt = 0; tt < 4; ++tt) s[mt][tt] = (f32x4){0.f, 0.f, 0.f, 0.f};
#pragma unroll
    for (int kc = 0; kc < 4; ++kc) {
      bf16x8 kf[4];
#pragma unroll
      for (int tt = 0; tt < 4; ++tt)
        kf[tt] = *(const bf16x8*)&Ks[tt * 16 + col][(((kc * 4 + quad) ^ col) & 15) * 8];
#pragma unroll
      for (int mt = 0; mt < 2; ++mt)
#pragma unroll
        for (int tt = 0; tt < 4; ++tt)
          s[mt][tt] = __builtin_amdgcn_mfma_f32_16x16x32_bf16(qf[mt][kc], kf[tt], s[mt][tt], 0, 0, 0);
    }

    // ---- online softmax (scores already in log2 domain, scale folded into Q) -----
#pragma unroll
    for (int mt = 0; mt < 2; ++mt)
#pragma unroll
      for (int r = 0; r < 4; ++r) {
        const int qabs = 1024 + qw + mt * 16 + quad * 4 + r;
        float v[4];
#pragma unroll
        for (int tt = 0; tt < 4; ++tt) {
          v[tt] = s[mt][tt][r];
          if (t0 + tt * 16 + col > qabs) v[tt] = -1e30f;
        }
        float mx = fmaxf(fmaxf(v[0], v[1]), fmaxf(v[2], v[3]));
        mx = fmaxf(mx, __shfl_xor(mx, 1));
        mx = fmaxf(mx, __shfl_xor(mx, 2));
        mx = fmaxf(mx, __shfl_xor(mx, 4));
        mx = fmaxf(mx, __shfl_xor(mx, 8));
        const float mnew  = fmaxf(m_r[mt][r], mx);
        const float alpha = fast_exp2(m_r[mt][r] - mnew);
        m_r[mt][r] = mnew;
        float sum = 0.f;
#pragma unroll
        for (int tt = 0; tt < 4; ++tt) {
          v[tt] = fast_exp2(v[tt] - mnew);
          sum += v[tt];
        }
        sum += __shfl_xor(sum, 1);
        sum += __shfl_xor(sum, 2);
        sum += __shfl_xor(sum, 4);
        sum += __shfl_xor(sum, 8);
        l_r[mt][r] = l_r[mt][r] * alpha + sum;
#pragma unroll
        for (int dt = 0; dt < 8; ++dt) o[mt][dt][r] *= alpha;
        // write P (C-layout -> chunk-swizzled LDS for A-operand reads)
        const int prow = mt * 16 + quad * 4 + r;
#pragma unroll
        for (int tt = 0; tt < 4; ++tt) {
          const int t = tt * 16 + col;
          const int c = (t >> 3) ^ (prow & 7);
          Plds[wave][prow][c * 8 + (t & 7)] = f2bf(v[tt]);
        }
      }
    asm volatile("s_waitcnt lgkmcnt(0)" ::: "memory");

    // ---- P fragments + PV --------------------------------------------------------
    bf16x8 pf[2][2];
#pragma unroll
    for (int mt = 0; mt < 2; ++mt)
#pragma unroll
      for (int kk = 0; kk < 2; ++kk)
        pf[mt][kk] = *(const bf16x8*)&Plds[wave][mt * 16 + col][(((kk * 4 + quad) ^ (col & 7))) * 8];
#pragma unroll
    for (int kk = 0; kk < 2; ++kk)
#pragma unroll
      for (int dt = 0; dt < 8; ++dt) {
        bf16x8 vf = *(const bf16x8*)&Vs[dt * 16 + col][(((kk * 4 + quad) ^ (col & 7))) * 8];
#pragma unroll
        for (int mt = 0; mt < 2; ++mt)
          o[mt][dt] = __builtin_amdgcn_mfma_f32_16x16x32_bf16(pf[mt][kk], vf, o[mt][dt], 0, 0, 0);
      }
    __syncthreads();   // Ks/Vs fully consumed before next staging
  }

  // ---- epilogue: normalize + store ctx bf16 (b, s, h, d) --------------------------
  float inv[2][4];
#pragma unroll
  for (int mt = 0; mt < 2; ++mt)
#pragma unroll
    for (int r = 0; r < 4; ++r) inv[mt][r] = 1.0f / l_r[mt][r];
#pragma unroll
  for (int mt = 0; mt < 2; ++mt)
#pragma unroll
    for (int dt = 0; dt < 8; ++dt)
#pragma unroll
      for (int r = 0; r < 4; ++r) {
        const int q = qw + mt * 16 + quad * 4 + r;
        const int d = dt * 16 + col;
        ctx[(size_t)(b * 1024 + q) * 4096 + h * 128 + d] = f2bf(o[mt][dt][r] * inv[mt][r]);
      }
}

// ----------------------------------------------------------------------------------
extern "C" void kernel_launch(void* const* d_in, const int* in_sizes, int n_in,
                              void* d_out, int out_size, void* d_ws, size_t ws_size,
                              hipStream_t stream) {
  const float* x    = (const float*)d_in[0];
  const float* kc   = (const float*)d_in[1];
  const float* vc   = (const float*)d_in[2];
  const float* rope = (const float*)d_in[3];
  const float* Wq   = (const float*)d_in[4];
  const float* Wk   = (const float*)d_in[5];
  const float* Wv   = (const float*)d_in[6];
  const float* Wo   = (const float*)d_in[7];

  float* out = (float*)d_out;                 // (2,1024,4096)
  float* xk  = out + 8388608;                 // (2,32,2048,128)
  float* xv  = out + 25165824;                // (2,32,2048,128)

  char* ws = (char*)d_ws;
  u16*   Xb   = (u16*)(ws + 0);               // x bf16          16,777,216 B
  u16*   Wc   = (u16*)(ws + 16777216);        // Wqkv bf16      100,663,296 B
  u16*   KbB  = (u16*)(ws + 16777216);        //   after GEMM1: K bf16 (b,h,2048,128)
  u16*   VTb  = (u16*)(ws + 50331648);        //   after GEMM1: V^T bf16 (b,h,128,2048)
  float* QKV  = (float*)(ws + 117440512);     // QKV fp32 (2048 x 12288)
  u16*   Wob  = (u16*)(ws + 117440512);       //   after rope: Wo bf16
  u16*   ctxb = (u16*)(ws + 150994944);       //   after rope: ctx bf16
  u16*   Qbb  = (u16*)(ws + 218103808);       // Q bf16 (b,h,1024,128), scale folded

  cvt_f32_bf16<<<8192, 256, 0, stream>>>(x, Xb, 8388608);
  cvt_f32_bf16<<<16384, 256, 0, stream>>>(Wq, Wc, 16777216);
  cvt_f32_bf16<<<16384, 256, 0, stream>>>(Wk, Wc + 16777216, 16777216);
  cvt_f32_bf16<<<16384, 256, 0, stream>>>(Wv, Wc + 33554432, 16777216);
  gemm_bt<<<dim3(96, 16), 256, 0, stream>>>(Xb, Wc, QKV, 2048, 12288, 4096);
  rope_q_kernel<<<16384, 256, 0, stream>>>(QKV, rope, Qbb);
  rope_k_kernel<<<16384, 256, 0, stream>>>(QKV, rope, xk, KbB);
  copy_v_kernel<<<32768, 256, 0, stream>>>(QKV, xv);
  cache_copy_k_kernel<<<32768, 256, 0, stream>>>(kc, xk, KbB);
  cache_copy_v_kernel<<<32768, 256, 0, stream>>>(vc, xv);
  transpose_v_kernel<<<dim3(64, 4, 64), 256, 0, stream>>>(xv, VTb);
  cvt_f32_bf16<<<16384, 256, 0, stream>>>(Wo, Wob, 16777216);
  attn_kernel<<<dim3(8, 64), 256, 0, stream>>>(Qbb, KbB, VTb, ctxb);
  gemm_bt<<<dim3(32, 16), 256, 0, stream>>>(ctxb, Wob, out, 2048, 4096, 4096);
}